// Round 1
// baseline (125.846 us; speedup 1.0000x reference)
//
#include <hip/hip_runtime.h>

// Fisher-Kolmogorov PDE: out = div(D * grad(u)) + rho * u * (1 - u)
// grad = central difference (0.5*(u[i+1]-u[i-1])) with replicate (edge) padding,
// applied twice (once for grad(u), once for grad(flux)) per axis.
// Shape: [B=4, C=1, D=192, H=192, W=192], all float32.

#define NX 192  // cube edge (D == H == W == 192)

__global__ __launch_bounds__(192)
void fk_kernel(const float* __restrict__ u,
               const float* __restrict__ Dd,
               const float* __restrict__ rho,
               float* __restrict__ out)
{
    const int x = threadIdx.x;          // 0..191 along W (contiguous)
    int row = blockIdx.x;               // (b*NX + z)*NX + y
    const int y = row % NX;
    row /= NX;
    const int z = row % NX;
    const int b = row / NX;

    const int base = ((b * NX + z) * NX + y) * NX + x;

    const float uc = u[base];

    // div contribution along one axis:
    //   f(j)  = D[j] * (u[clamp(j+1)] - u[clamp(j-1)])      (x0.5 folded below)
    //   div   = (f(clamp(c+1)) - f(clamp(c-1))) * 0.25
    // For n=192 and c in [0,191]: jp=min(c+1,191) >= 1 so jp-1 needs no clamp;
    // jm=max(c-1,0) <= 190 so jm+1 needs no clamp.
    auto divterm = [&](int c, int stride) -> float {
        const int n = NX;
        const int jp  = (c + 1 < n) ? (c + 1) : (n - 1);
        const int jm  = (c - 1 > 0) ? (c - 1) : 0;
        const int jpp = (jp + 1 < n) ? (jp + 1) : (n - 1);
        const int jpm = jp - 1;                         // >= 0 always
        const int jmp = jm + 1;                         // <= n-1 always
        const int jmm = (jm - 1 > 0) ? (jm - 1) : 0;

        const float fp = Dd[base + (jp - c) * stride] *
                         (u[base + (jpp - c) * stride] - u[base + (jpm - c) * stride]);
        const float fm = Dd[base + (jm - c) * stride] *
                         (u[base + (jmp - c) * stride] - u[base + (jmm - c) * stride]);
        return (fp - fm) * 0.25f;
    };

    const float dx = divterm(x, 1);
    const float dy = divterm(y, NX);
    const float dz = divterm(z, NX * NX);

    const float reaction = rho[base] * uc * (1.0f - uc);

    out[base] = dx + dy + dz + reaction;
}

extern "C" void kernel_launch(void* const* d_in, const int* in_sizes, int n_in,
                              void* d_out, int out_size, void* d_ws, size_t ws_size,
                              hipStream_t stream) {
    const float* u   = (const float*)d_in[0];
    const float* Dd  = (const float*)d_in[1];
    const float* rho = (const float*)d_in[2];
    float* out = (float*)d_out;

    const int B = 4;  // batch * channel
    const int rows = B * NX * NX;   // one block per contiguous x-row

    fk_kernel<<<rows, NX, 0, stream>>>(u, Dd, rho, out);
}